// Round 1
// baseline (663.639 us; speedup 1.0000x reference)
//
#include <hip/hip_runtime.h>
#include <math.h>

#define NN 100000
#define NE 1600000
#define IND 128
#define OUTD 64
#define ED 16
#define NH 4
#define HD 16
#define NB1 98      // ceil(NN/1024) for scan phase 1

typedef float f4v __attribute__((ext_vector_type(4)));

// ---------------- zero degree histogram ----------------
__global__ void k_zero(int* __restrict__ deg) {
    int i = blockIdx.x * 256 + threadIdx.x;
    if (i < NN) deg[i] = 0;
}

// ---------------- node GEMM + attention scalars --------
// loop-interchanged: W-values loaded once per K-step, shared across 4 rows
__global__ __launch_bounds__(256) void k_node(
        const float* __restrict__ x, const float* __restrict__ Wn,
        const float* __restrict__ att_s, const float* __restrict__ att_d,
        float* __restrict__ Wh, float* __restrict__ asrc, float* __restrict__ adst) {
    __shared__ float sWt[IND * OUTD];   // 32 KB, [k][c]
    __shared__ float sx[16][IND];       // 8 KB
    int tid = threadIdx.x;
    {
        int c = tid & 63;
        for (int k4 = tid >> 6; k4 < IND / 4; k4 += 4) {
            float4 v = ((const float4*)Wn)[c * (IND / 4) + k4];
            sWt[(k4 * 4 + 0) * OUTD + c] = v.x;
            sWt[(k4 * 4 + 1) * OUTD + c] = v.y;
            sWt[(k4 * 4 + 2) * OUTD + c] = v.z;
            sWt[(k4 * 4 + 3) * OUTD + c] = v.w;
        }
    }
    long long rowBase = (long long)blockIdx.x * 16;
    for (int i = tid; i < 16 * (IND / 4); i += 256) {
        int r = i >> 5, k4 = i & 31;
        long long row = rowBase + r;
        float4 v = make_float4(0.f, 0.f, 0.f, 0.f);
        if (row < NN) v = ((const float4*)x)[row * (IND / 4) + k4];
        ((float4*)sx)[r * (IND / 4) + k4] = v;
    }
    __syncthreads();

    int wave = tid >> 6, lane = tid & 63;
    float acc[4] = {0.f, 0.f, 0.f, 0.f};
    const float4* xr0 = (const float4*)&sx[wave * 4 + 0][0];
    const float4* xr1 = (const float4*)&sx[wave * 4 + 1][0];
    const float4* xr2 = (const float4*)&sx[wave * 4 + 2][0];
    const float4* xr3 = (const float4*)&sx[wave * 4 + 3][0];
#pragma unroll
    for (int k4 = 0; k4 < IND / 4; k4++) {
        float w0 = sWt[(k4 * 4 + 0) * OUTD + lane];
        float w1 = sWt[(k4 * 4 + 1) * OUTD + lane];
        float w2 = sWt[(k4 * 4 + 2) * OUTD + lane];
        float w3 = sWt[(k4 * 4 + 3) * OUTD + lane];
        float4 x0 = xr0[k4], x1 = xr1[k4], x2 = xr2[k4], x3 = xr3[k4];
        acc[0] += x0.x * w0 + x0.y * w1 + x0.z * w2 + x0.w * w3;
        acc[1] += x1.x * w0 + x1.y * w1 + x1.z * w2 + x1.w * w3;
        acc[2] += x2.x * w0 + x2.y * w1 + x2.z * w2 + x2.w * w3;
        acc[3] += x3.x * w0 + x3.y * w1 + x3.z * w2 + x3.w * w3;
    }
    float as = att_s[lane];
    float ad = att_d[lane];
#pragma unroll
    for (int rr = 0; rr < 4; rr++) {
        long long row = rowBase + wave * 4 + rr;
        if (row >= NN) continue;
        Wh[row * OUTD + lane] = acc[rr];
        float vs = acc[rr] * as, vd = acc[rr] * ad;
#pragma unroll
        for (int m = 1; m < 16; m <<= 1) {
            vs += __shfl_xor(vs, m);
            vd += __shfl_xor(vd, m);
        }
        if ((lane & 15) == 0) {
            int h = lane >> 4;
            asrc[row * NH + h] = vs;
            adst[row * NH + h] = vd;
        }
    }
}

// ---------------- degree histogram (4 edges/thread) ----------------
__global__ void k_hist(const int* __restrict__ ei, int* __restrict__ deg) {
    int i = blockIdx.x * 256 + threadIdx.x;
    if (i < NE / 4) {
        int4 dv = ((const int4*)(ei + NE))[i];
        atomicAdd(&deg[dv.x], 1);
        atomicAdd(&deg[dv.y], 1);
        atomicAdd(&deg[dv.z], 1);
        atomicAdd(&deg[dv.w], 1);
    }
}

// ---------------- 3-phase exclusive scan over deg[NN] ----------------
__global__ __launch_bounds__(256) void k_scan1(const int* __restrict__ deg,
                                               int* __restrict__ offA,
                                               int* __restrict__ bsum) {
    __shared__ int sd[256];
    int b = blockIdx.x, t = threadIdx.x;
    int base = b * 1024 + t * 4;
    int v0 = 0, v1 = 0, v2 = 0, v3 = 0;
    if (base + 0 < NN) v0 = deg[base + 0];
    if (base + 1 < NN) v1 = deg[base + 1];
    if (base + 2 < NN) v2 = deg[base + 2];
    if (base + 3 < NN) v3 = deg[base + 3];
    int s = v0 + v1 + v2 + v3;
    sd[t] = s;
    __syncthreads();
    for (int ofs = 1; ofs < 256; ofs <<= 1) {
        int xv = 0;
        if (t >= ofs) xv = sd[t - ofs];
        __syncthreads();
        sd[t] += xv;
        __syncthreads();
    }
    int excl = sd[t] - s;
    if (base + 0 < NN) offA[base + 0] = excl;
    if (base + 1 < NN) offA[base + 1] = excl + v0;
    if (base + 2 < NN) offA[base + 2] = excl + v0 + v1;
    if (base + 3 < NN) offA[base + 3] = excl + v0 + v1 + v2;
    if (t == 255) bsum[b] = sd[255];
}

__global__ __launch_bounds__(128) void k_scan2(int* __restrict__ bsum) {
    __shared__ int sd[128];
    int t = threadIdx.x;
    int v = (t < NB1) ? bsum[t] : 0;
    sd[t] = v;
    __syncthreads();
    for (int ofs = 1; ofs < 128; ofs <<= 1) {
        int xv = 0;
        if (t >= ofs) xv = sd[t - ofs];
        __syncthreads();
        sd[t] += xv;
        __syncthreads();
    }
    if (t < NB1) bsum[t] = sd[t] - v;  // exclusive
}

__global__ void k_scan3(const int* __restrict__ offA, const int* __restrict__ bsum,
                        int* __restrict__ off, int* __restrict__ pos) {
    int i = blockIdx.x * 256 + threadIdx.x;
    if (i < NN) {
        int v = offA[i] + bsum[i >> 10];
        off[i] = v;
        pos[i] = v;
    }
    if (i == 0) off[NN] = NE;
}

// ---------------- edge scores -> exp, packed 16B CSR scatter ----------
// record @ rec + 4*p floats: [ex0 ex1 ex2 ex3] with src's 17 bits packed
// into the low mantissa bits (5+4+4+4) — rel. error <= ~4e-6, invisible.
// 4 edges/thread; all atomics issued up-front to overlap their latency.
__global__ __launch_bounds__(256) void k_edge(
        const int* __restrict__ ei, const float* __restrict__ ea,
        const float* __restrict__ We, const float* __restrict__ asrc,
        const float* __restrict__ adst, int* __restrict__ pos,
        float* __restrict__ rec) {
    __shared__ float sWe[NH * ED];
    if (threadIdx.x < NH * ED) sWe[threadIdx.x] = We[threadIdx.x];
    __syncthreads();
    int base = blockIdx.x * 1024 + threadIdx.x;
    int s[4], d[4], p[4];
    bool ok[4];
#pragma unroll
    for (int k = 0; k < 4; k++) {
        int e = base + k * 256;
        ok[k] = (e < NE);
        s[k] = ok[k] ? ei[e] : 0;
        d[k] = ok[k] ? ei[NE + e] : 0;
    }
#pragma unroll
    for (int k = 0; k < 4; k++)
        p[k] = ok[k] ? atomicAdd(&pos[d[k]], 1) : 0;
    float4 as_[4], ad_[4];
#pragma unroll
    for (int k = 0; k < 4; k++) {
        as_[k] = ok[k] ? *(const float4*)(asrc + (long long)s[k] * NH) : make_float4(0.f, 0.f, 0.f, 0.f);
        ad_[k] = ok[k] ? *(const float4*)(adst + (long long)d[k] * NH) : make_float4(0.f, 0.f, 0.f, 0.f);
    }
#pragma unroll
    for (int k = 0; k < 4; k++) {
        if (!ok[k]) continue;
        long long e = base + k * 256;
        f4v* ea4 = (f4v*)(const_cast<float*>(ea) + e * ED);
        f4v q0 = __builtin_nontemporal_load(ea4 + 0);
        f4v q1 = __builtin_nontemporal_load(ea4 + 1);
        f4v q2 = __builtin_nontemporal_load(ea4 + 2);
        f4v q3 = __builtin_nontemporal_load(ea4 + 3);
        float asv[4] = {as_[k].x, as_[k].y, as_[k].z, as_[k].w};
        float adv[4] = {ad_[k].x, ad_[k].y, ad_[k].z, ad_[k].w};
        unsigned int u[4];
#pragma unroll
        for (int h = 0; h < NH; h++) {
            const float* w = sWe + h * ED;
            float t = asv[h] + adv[h];
            t += q0.x * w[0]  + q0.y * w[1]  + q0.z * w[2]  + q0.w * w[3];
            t += q1.x * w[4]  + q1.y * w[5]  + q1.z * w[6]  + q1.w * w[7];
            t += q2.x * w[8]  + q2.y * w[9]  + q2.z * w[10] + q2.w * w[11];
            t += q3.x * w[12] + q3.y * w[13] + q3.z * w[14] + q3.w * w[15];
            t = (t >= 0.f) ? t : 0.2f * t;
            u[h] = __float_as_uint(expf(t));   // max score ~ +12 -> exp ~ 1.6e5, safe in f32
        }
        unsigned int ss = (unsigned int)s[k];
        u[0] = (u[0] & ~31u) | (ss & 31u);
        u[1] = (u[1] & ~15u) | ((ss >> 5) & 15u);
        u[2] = (u[2] & ~15u) | ((ss >> 9) & 15u);
        u[3] = (u[3] & ~15u) | ((ss >> 13) & 15u);
        f4v rv = {__uint_as_float(u[0]), __uint_as_float(u[1]),
                  __uint_as_float(u[2]), __uint_as_float(u[3])};
        __builtin_nontemporal_store(rv, (f4v*)rec + p[k]);
    }
}

// ---------------- gather: normalize + accumulate + elu --------------
// wave per node; 4 groups of 16 lanes; group g handles edges j = start+g, +4...
// lane holds channels c16*4..c16*4+3 (float4); head h = c16>>2.
// no expf here: records already hold exp(score); src decoded from mantissa bits
__global__ __launch_bounds__(256) void k_gather(
        const int* __restrict__ off, float* __restrict__ rec,
        const float* __restrict__ Wh, const float* __restrict__ bias,
        float* __restrict__ out) {
    int node = blockIdx.x * 4 + (threadIdx.x >> 6);
    int lane = threadIdx.x & 63;
    if (node >= NN) return;
    int start = off[node], end = off[node + 1];
    int g = lane >> 4;       // edge group
    int c16 = lane & 15;     // channel quad
    int h = c16 >> 2;        // head

    float accx = 0.f, accy = 0.f, accz = 0.f, accw = 0.f;
    float dsum = 0.f;
#pragma unroll 2
    for (int j = start + g; j < end; j += 4) {
        f4v r = __builtin_nontemporal_load((f4v*)rec + j);   // 16-lane broadcast
        unsigned int b0 = __float_as_uint(r.x), b1 = __float_as_uint(r.y);
        unsigned int b2 = __float_as_uint(r.z), b3 = __float_as_uint(r.w);
        int src = (int)((b0 & 31u) | ((b1 & 15u) << 5) | ((b2 & 15u) << 9) | ((b3 & 15u) << 13));
        float ex = (h == 0) ? r.x : (h == 1) ? r.y : (h == 2) ? r.z : r.w;
        float4 w = *(const float4*)(Wh + (long long)src * OUTD + c16 * 4);
        accx += ex * w.x;
        accy += ex * w.y;
        accz += ex * w.z;
        accw += ex * w.w;
        dsum += ex;
    }
    // combine the 4 edge-groups (lanes l, l+16, l+32, l+48 share c16)
#pragma unroll
    for (int m = 16; m < 64; m <<= 1) {
        accx += __shfl_xor(accx, m);
        accy += __shfl_xor(accy, m);
        accz += __shfl_xor(accz, m);
        accw += __shfl_xor(accw, m);
        dsum += __shfl_xor(dsum, m);
    }
    if (g == 0) {
        float rden = 1.0f / (dsum + 1e-9f);
        const float4 b4 = *(const float4*)(bias + c16 * 4);
        float vx = accx * rden + b4.x;
        float vy = accy * rden + b4.y;
        float vz = accz * rden + b4.z;
        float vw = accw * rden + b4.w;
        vx = (vx > 0.f) ? vx : expm1f(vx);
        vy = (vy > 0.f) ? vy : expm1f(vy);
        vz = (vz > 0.f) ? vz : expm1f(vz);
        vw = (vw > 0.f) ? vw : expm1f(vw);
        f4v v = {vx, vy, vz, vw};
        __builtin_nontemporal_store(v, (f4v*)(out + (long long)node * OUTD) + c16);
    }
}

extern "C" void kernel_launch(void* const* d_in, const int* in_sizes, int n_in,
                              void* d_out, int out_size, void* d_ws, size_t ws_size,
                              hipStream_t stream) {
    const float* x     = (const float*)d_in[0];   // [NN,128]
    const int*   ei    = (const int*)d_in[1];     // [2,NE]
    const float* ea    = (const float*)d_in[2];   // [NE,16]
    const float* Wn    = (const float*)d_in[3];   // [64,128]
    const float* We    = (const float*)d_in[4];   // [4,16]
    const float* att_s = (const float*)d_in[5];   // 64
    const float* att_d = (const float*)d_in[6];   // 64
    const float* bias  = (const float*)d_in[7];   // 64
    float* out = (float*)d_out;

    float* ws   = (float*)d_ws;
    float* Wh   = ws;                                   // NN*64 f
    float* asrc = Wh + (size_t)NN * OUTD;               // NN*4 f
    float* adst = asrc + (size_t)NN * NH;               // NN*4 f
    float* rec  = adst + (size_t)NN * NH;               // NE*4 f (packed 16B records)
    int*   deg  = (int*)(rec + (size_t)NE * 4);         // NN i
    int*   offA = deg + NN;                             // NN i
    int*   off  = offA + NN;                            // NN+1 i
    int*   pos  = off + NN + 1;                         // NN i
    int*   bsum = pos + NN;                             // 128 i

    k_zero<<<(NN + 255) / 256, 256, 0, stream>>>(deg);
    k_node<<<(NN + 15) / 16, 256, 0, stream>>>(x, Wn, att_s, att_d, Wh, asrc, adst);
    k_hist<<<(NE / 4 + 255) / 256, 256, 0, stream>>>(ei, deg);
    k_scan1<<<NB1, 256, 0, stream>>>(deg, offA, bsum);
    k_scan2<<<1, 128, 0, stream>>>(bsum);
    k_scan3<<<(NN + 255) / 256, 256, 0, stream>>>(offA, bsum, off, pos);
    k_edge<<<(NE + 1023) / 1024, 256, 0, stream>>>(ei, ea, We, asrc, adst, pos, rec);
    k_gather<<<(NN + 3) / 4, 256, 0, stream>>>(off, rec, Wh, bias, out);
}

// Round 2
// 524.782 us; speedup vs baseline: 1.2646x; 1.2646x over previous
//
#include <hip/hip_runtime.h>
#include <math.h>

#define NN 100000
#define NE 1600000
#define IND 128
#define OUTD 64
#define ED 16
#define NH 4
#define HD 16
#define NB1 98      // ceil(NN/1024) for scan phase 1

typedef float f4v __attribute__((ext_vector_type(4)));

// ---------------- zero degree histogram ----------------
__global__ void k_zero(int* __restrict__ deg) {
    int i = blockIdx.x * 256 + threadIdx.x;
    if (i < NN) deg[i] = 0;
}

// ---------------- node GEMM + attention scalars --------
// loop-interchanged: W-values loaded once per K-step, shared across 4 rows.
// outer k-loop NOT unrolled (pragma unroll 1) — full unroll blew VGPR to 256
// and spilled (round-1 post-mortem: WRITE_SIZE +7MB scratch, occupancy 11%).
__global__ __launch_bounds__(256) void k_node(
        const float* __restrict__ x, const float* __restrict__ Wn,
        const float* __restrict__ att_s, const float* __restrict__ att_d,
        float* __restrict__ Wh, float* __restrict__ asrc, float* __restrict__ adst) {
    __shared__ float sWt[IND * OUTD];   // 32 KB, [k][c]
    __shared__ float sx[16][IND];       // 8 KB
    int tid = threadIdx.x;
    {
        int c = tid & 63;
        for (int k4 = tid >> 6; k4 < IND / 4; k4 += 4) {
            float4 v = ((const float4*)Wn)[c * (IND / 4) + k4];
            sWt[(k4 * 4 + 0) * OUTD + c] = v.x;
            sWt[(k4 * 4 + 1) * OUTD + c] = v.y;
            sWt[(k4 * 4 + 2) * OUTD + c] = v.z;
            sWt[(k4 * 4 + 3) * OUTD + c] = v.w;
        }
    }
    long long rowBase = (long long)blockIdx.x * 16;
    for (int i = tid; i < 16 * (IND / 4); i += 256) {
        int r = i >> 5, k4 = i & 31;
        long long row = rowBase + r;
        float4 v = make_float4(0.f, 0.f, 0.f, 0.f);
        if (row < NN) v = ((const float4*)x)[row * (IND / 4) + k4];
        ((float4*)sx)[r * (IND / 4) + k4] = v;
    }
    __syncthreads();

    int wave = tid >> 6, lane = tid & 63;
    float acc0 = 0.f, acc1 = 0.f, acc2 = 0.f, acc3 = 0.f;
    const float4* xr0 = (const float4*)&sx[wave * 4 + 0][0];
    const float4* xr1 = (const float4*)&sx[wave * 4 + 1][0];
    const float4* xr2 = (const float4*)&sx[wave * 4 + 2][0];
    const float4* xr3 = (const float4*)&sx[wave * 4 + 3][0];
#pragma unroll 1
    for (int kk = 0; kk < IND / 16; kk++) {
#pragma unroll
        for (int j = 0; j < 4; j++) {
            int k4 = kk * 4 + j;
            float w0 = sWt[(k4 * 4 + 0) * OUTD + lane];
            float w1 = sWt[(k4 * 4 + 1) * OUTD + lane];
            float w2 = sWt[(k4 * 4 + 2) * OUTD + lane];
            float w3 = sWt[(k4 * 4 + 3) * OUTD + lane];
            float4 x0 = xr0[k4], x1 = xr1[k4], x2 = xr2[k4], x3 = xr3[k4];
            acc0 += x0.x * w0 + x0.y * w1 + x0.z * w2 + x0.w * w3;
            acc1 += x1.x * w0 + x1.y * w1 + x1.z * w2 + x1.w * w3;
            acc2 += x2.x * w0 + x2.y * w1 + x2.z * w2 + x2.w * w3;
            acc3 += x3.x * w0 + x3.y * w1 + x3.z * w2 + x3.w * w3;
        }
    }
    float as = att_s[lane];
    float ad = att_d[lane];
    float accs[4] = {acc0, acc1, acc2, acc3};
#pragma unroll
    for (int rr = 0; rr < 4; rr++) {
        long long row = rowBase + wave * 4 + rr;
        if (row >= NN) continue;
        Wh[row * OUTD + lane] = accs[rr];
        float vs = accs[rr] * as, vd = accs[rr] * ad;
#pragma unroll
        for (int m = 1; m < 16; m <<= 1) {
            vs += __shfl_xor(vs, m);
            vd += __shfl_xor(vd, m);
        }
        if ((lane & 15) == 0) {
            int h = lane >> 4;
            asrc[row * NH + h] = vs;
            adst[row * NH + h] = vd;
        }
    }
}

// ---------------- degree histogram (4 edges/thread) ----------------
__global__ void k_hist(const int* __restrict__ ei, int* __restrict__ deg) {
    int i = blockIdx.x * 256 + threadIdx.x;
    if (i < NE / 4) {
        int4 dv = ((const int4*)(ei + NE))[i];
        atomicAdd(&deg[dv.x], 1);
        atomicAdd(&deg[dv.y], 1);
        atomicAdd(&deg[dv.z], 1);
        atomicAdd(&deg[dv.w], 1);
    }
}

// ---------------- 3-phase exclusive scan over deg[NN] ----------------
__global__ __launch_bounds__(256) void k_scan1(const int* __restrict__ deg,
                                               int* __restrict__ offA,
                                               int* __restrict__ bsum) {
    __shared__ int sd[256];
    int b = blockIdx.x, t = threadIdx.x;
    int base = b * 1024 + t * 4;
    int v0 = 0, v1 = 0, v2 = 0, v3 = 0;
    if (base + 0 < NN) v0 = deg[base + 0];
    if (base + 1 < NN) v1 = deg[base + 1];
    if (base + 2 < NN) v2 = deg[base + 2];
    if (base + 3 < NN) v3 = deg[base + 3];
    int s = v0 + v1 + v2 + v3;
    sd[t] = s;
    __syncthreads();
    for (int ofs = 1; ofs < 256; ofs <<= 1) {
        int xv = 0;
        if (t >= ofs) xv = sd[t - ofs];
        __syncthreads();
        sd[t] += xv;
        __syncthreads();
    }
    int excl = sd[t] - s;
    if (base + 0 < NN) offA[base + 0] = excl;
    if (base + 1 < NN) offA[base + 1] = excl + v0;
    if (base + 2 < NN) offA[base + 2] = excl + v0 + v1;
    if (base + 3 < NN) offA[base + 3] = excl + v0 + v1 + v2;
    if (t == 255) bsum[b] = sd[255];
}

__global__ __launch_bounds__(128) void k_scan2(int* __restrict__ bsum) {
    __shared__ int sd[128];
    int t = threadIdx.x;
    int v = (t < NB1) ? bsum[t] : 0;
    sd[t] = v;
    __syncthreads();
    for (int ofs = 1; ofs < 128; ofs <<= 1) {
        int xv = 0;
        if (t >= ofs) xv = sd[t - ofs];
        __syncthreads();
        sd[t] += xv;
        __syncthreads();
    }
    if (t < NB1) bsum[t] = sd[t] - v;  // exclusive
}

__global__ void k_scan3(const int* __restrict__ offA, const int* __restrict__ bsum,
                        int* __restrict__ off, int* __restrict__ pos) {
    int i = blockIdx.x * 256 + threadIdx.x;
    if (i < NN) {
        int v = offA[i] + bsum[i >> 10];
        off[i] = v;
        pos[i] = v;
    }
    if (i == 0) off[NN] = NE;
}

// ---------------- edge scores -> exp, packed 16B CSR scatter ----------
// record @ rec + 4*p floats: [ex0 ex1 ex2 ex3] with src's 17 bits packed
// into the low mantissa bits (5+4+4+4) — rel. error <= ~4e-6, invisible.
// 4 edges/thread; all atomics issued up-front to overlap their latency.
__global__ __launch_bounds__(256) void k_edge(
        const int* __restrict__ ei, const float* __restrict__ ea,
        const float* __restrict__ We, const float* __restrict__ asrc,
        const float* __restrict__ adst, int* __restrict__ pos,
        float* __restrict__ rec) {
    __shared__ float sWe[NH * ED];
    if (threadIdx.x < NH * ED) sWe[threadIdx.x] = We[threadIdx.x];
    __syncthreads();
    int base = blockIdx.x * 1024 + threadIdx.x;
    int s[4], d[4], p[4];
    bool ok[4];
#pragma unroll
    for (int k = 0; k < 4; k++) {
        int e = base + k * 256;
        ok[k] = (e < NE);
        s[k] = ok[k] ? ei[e] : 0;
        d[k] = ok[k] ? ei[NE + e] : 0;
    }
#pragma unroll
    for (int k = 0; k < 4; k++)
        p[k] = ok[k] ? atomicAdd(&pos[d[k]], 1) : 0;
    float4 as_[4], ad_[4];
#pragma unroll
    for (int k = 0; k < 4; k++) {
        as_[k] = ok[k] ? *(const float4*)(asrc + (long long)s[k] * NH) : make_float4(0.f, 0.f, 0.f, 0.f);
        ad_[k] = ok[k] ? *(const float4*)(adst + (long long)d[k] * NH) : make_float4(0.f, 0.f, 0.f, 0.f);
    }
#pragma unroll
    for (int k = 0; k < 4; k++) {
        if (!ok[k]) continue;
        long long e = base + k * 256;
        f4v* ea4 = (f4v*)(const_cast<float*>(ea) + e * ED);
        f4v q0 = __builtin_nontemporal_load(ea4 + 0);
        f4v q1 = __builtin_nontemporal_load(ea4 + 1);
        f4v q2 = __builtin_nontemporal_load(ea4 + 2);
        f4v q3 = __builtin_nontemporal_load(ea4 + 3);
        float asv[4] = {as_[k].x, as_[k].y, as_[k].z, as_[k].w};
        float adv[4] = {ad_[k].x, ad_[k].y, ad_[k].z, ad_[k].w};
        unsigned int u[4];
#pragma unroll
        for (int h = 0; h < NH; h++) {
            const float* w = sWe + h * ED;
            float t = asv[h] + adv[h];
            t += q0.x * w[0]  + q0.y * w[1]  + q0.z * w[2]  + q0.w * w[3];
            t += q1.x * w[4]  + q1.y * w[5]  + q1.z * w[6]  + q1.w * w[7];
            t += q2.x * w[8]  + q2.y * w[9]  + q2.z * w[10] + q2.w * w[11];
            t += q3.x * w[12] + q3.y * w[13] + q3.z * w[14] + q3.w * w[15];
            t = (t >= 0.f) ? t : 0.2f * t;
            u[h] = __float_as_uint(expf(t));   // max score ~ +12 -> exp ~ 1.6e5, safe in f32
        }
        unsigned int ss = (unsigned int)s[k];
        u[0] = (u[0] & ~31u) | (ss & 31u);
        u[1] = (u[1] & ~15u) | ((ss >> 5) & 15u);
        u[2] = (u[2] & ~15u) | ((ss >> 9) & 15u);
        u[3] = (u[3] & ~15u) | ((ss >> 13) & 15u);
        f4v rv = {__uint_as_float(u[0]), __uint_as_float(u[1]),
                  __uint_as_float(u[2]), __uint_as_float(u[3])};
        __builtin_nontemporal_store(rv, (f4v*)rec + p[k]);
    }
}

// ---------------- gather: normalize + accumulate + elu --------------
// wave per node; 4 groups of 16 lanes; group g handles edges j = start+g, +4...
// lane holds channels c16*4..c16*4+3 (float4); head h = c16>>2.
// no expf here: records already hold exp(score); src decoded from mantissa bits
__global__ __launch_bounds__(256) void k_gather(
        const int* __restrict__ off, float* __restrict__ rec,
        const float* __restrict__ Wh, const float* __restrict__ bias,
        float* __restrict__ out) {
    int node = blockIdx.x * 4 + (threadIdx.x >> 6);
    int lane = threadIdx.x & 63;
    if (node >= NN) return;
    int start = off[node], end = off[node + 1];
    int g = lane >> 4;       // edge group
    int c16 = lane & 15;     // channel quad
    int h = c16 >> 2;        // head

    float accx = 0.f, accy = 0.f, accz = 0.f, accw = 0.f;
    float dsum = 0.f;
#pragma unroll 2
    for (int j = start + g; j < end; j += 4) {
        f4v r = __builtin_nontemporal_load((f4v*)rec + j);   // 16-lane broadcast
        unsigned int b0 = __float_as_uint(r.x), b1 = __float_as_uint(r.y);
        unsigned int b2 = __float_as_uint(r.z), b3 = __float_as_uint(r.w);
        int src = (int)((b0 & 31u) | ((b1 & 15u) << 5) | ((b2 & 15u) << 9) | ((b3 & 15u) << 13));
        float ex = (h == 0) ? r.x : (h == 1) ? r.y : (h == 2) ? r.z : r.w;
        float4 w = *(const float4*)(Wh + (long long)src * OUTD + c16 * 4);
        accx += ex * w.x;
        accy += ex * w.y;
        accz += ex * w.z;
        accw += ex * w.w;
        dsum += ex;
    }
    // combine the 4 edge-groups (lanes l, l+16, l+32, l+48 share c16)
#pragma unroll
    for (int m = 16; m < 64; m <<= 1) {
        accx += __shfl_xor(accx, m);
        accy += __shfl_xor(accy, m);
        accz += __shfl_xor(accz, m);
        accw += __shfl_xor(accw, m);
        dsum += __shfl_xor(dsum, m);
    }
    if (g == 0) {
        float rden = 1.0f / (dsum + 1e-9f);
        const float4 b4 = *(const float4*)(bias + c16 * 4);
        float vx = accx * rden + b4.x;
        float vy = accy * rden + b4.y;
        float vz = accz * rden + b4.z;
        float vw = accw * rden + b4.w;
        vx = (vx > 0.f) ? vx : expm1f(vx);
        vy = (vy > 0.f) ? vy : expm1f(vy);
        vz = (vz > 0.f) ? vz : expm1f(vz);
        vw = (vw > 0.f) ? vw : expm1f(vw);
        f4v v = {vx, vy, vz, vw};
        __builtin_nontemporal_store(v, (f4v*)(out + (long long)node * OUTD) + c16);
    }
}

extern "C" void kernel_launch(void* const* d_in, const int* in_sizes, int n_in,
                              void* d_out, int out_size, void* d_ws, size_t ws_size,
                              hipStream_t stream) {
    const float* x     = (const float*)d_in[0];   // [NN,128]
    const int*   ei    = (const int*)d_in[1];     // [2,NE]
    const float* ea    = (const float*)d_in[2];   // [NE,16]
    const float* Wn    = (const float*)d_in[3];   // [64,128]
    const float* We    = (const float*)d_in[4];   // [4,16]
    const float* att_s = (const float*)d_in[5];   // 64
    const float* att_d = (const float*)d_in[6];   // 64
    const float* bias  = (const float*)d_in[7];   // 64
    float* out = (float*)d_out;

    float* ws   = (float*)d_ws;
    float* Wh   = ws;                                   // NN*64 f
    float* asrc = Wh + (size_t)NN * OUTD;               // NN*4 f
    float* adst = asrc + (size_t)NN * NH;               // NN*4 f
    float* rec  = adst + (size_t)NN * NH;               // NE*4 f (packed 16B records)
    int*   deg  = (int*)(rec + (size_t)NE * 4);         // NN i
    int*   offA = deg + NN;                             // NN i
    int*   off  = offA + NN;                            // NN+1 i
    int*   pos  = off + NN + 1;                         // NN i
    int*   bsum = pos + NN;                             // 128 i

    k_zero<<<(NN + 255) / 256, 256, 0, stream>>>(deg);
    k_node<<<(NN + 15) / 16, 256, 0, stream>>>(x, Wn, att_s, att_d, Wh, asrc, adst);
    k_hist<<<(NE / 4 + 255) / 256, 256, 0, stream>>>(ei, deg);
    k_scan1<<<NB1, 256, 0, stream>>>(deg, offA, bsum);
    k_scan2<<<1, 128, 0, stream>>>(bsum);
    k_scan3<<<(NN + 255) / 256, 256, 0, stream>>>(offA, bsum, off, pos);
    k_edge<<<(NE + 1023) / 1024, 256, 0, stream>>>(ei, ea, We, asrc, adst, pos, rec);
    k_gather<<<(NN + 3) / 4, 256, 0, stream>>>(off, rec, Wh, bias, out);
}

// Round 3
// 482.908 us; speedup vs baseline: 1.3743x; 1.0867x over previous
//
#include <hip/hip_runtime.h>
#include <math.h>

#define NN 100000
#define NE 1600000
#define IND 128
#define OUTD 64
#define ED 16
#define NH 4
#define HD 16
#define NB1 98      // ceil(NN/1024) for scan phase 1

typedef float f4v __attribute__((ext_vector_type(4)));

// ---------------- node GEMM + attention scalars (+ fused deg zero) --------
// loop-interchanged: W-values loaded once per K-step, shared across 4 rows.
// outer k-loop NOT unrolled (pragma unroll 1) — full unroll blew VGPR to 256
// and spilled (round-1 post-mortem: WRITE_SIZE +7MB scratch, occupancy 11%).
__global__ __launch_bounds__(256) void k_node(
        const float* __restrict__ x, const float* __restrict__ Wn,
        const float* __restrict__ att_s, const float* __restrict__ att_d,
        float* __restrict__ Wh, float* __restrict__ asrc, float* __restrict__ adst,
        int* __restrict__ deg) {
    __shared__ float sWt[IND * OUTD];   // 32 KB, [k][c]
    __shared__ float sx[16][IND];       // 8 KB
    int tid = threadIdx.x;
    long long rowBase = (long long)blockIdx.x * 16;
    // fused deg zeroing (k_hist runs only after this kernel completes)
    if (tid < 16 && rowBase + tid < NN) deg[rowBase + tid] = 0;
    {
        int c = tid & 63;
        for (int k4 = tid >> 6; k4 < IND / 4; k4 += 4) {
            float4 v = ((const float4*)Wn)[c * (IND / 4) + k4];
            sWt[(k4 * 4 + 0) * OUTD + c] = v.x;
            sWt[(k4 * 4 + 1) * OUTD + c] = v.y;
            sWt[(k4 * 4 + 2) * OUTD + c] = v.z;
            sWt[(k4 * 4 + 3) * OUTD + c] = v.w;
        }
    }
    for (int i = tid; i < 16 * (IND / 4); i += 256) {
        int r = i >> 5, k4 = i & 31;
        long long row = rowBase + r;
        float4 v = make_float4(0.f, 0.f, 0.f, 0.f);
        if (row < NN) v = ((const float4*)x)[row * (IND / 4) + k4];
        ((float4*)sx)[r * (IND / 4) + k4] = v;
    }
    __syncthreads();

    int wave = tid >> 6, lane = tid & 63;
    float acc0 = 0.f, acc1 = 0.f, acc2 = 0.f, acc3 = 0.f;
    const float4* xr0 = (const float4*)&sx[wave * 4 + 0][0];
    const float4* xr1 = (const float4*)&sx[wave * 4 + 1][0];
    const float4* xr2 = (const float4*)&sx[wave * 4 + 2][0];
    const float4* xr3 = (const float4*)&sx[wave * 4 + 3][0];
#pragma unroll 1
    for (int kk = 0; kk < IND / 16; kk++) {
#pragma unroll
        for (int j = 0; j < 4; j++) {
            int k4 = kk * 4 + j;
            float w0 = sWt[(k4 * 4 + 0) * OUTD + lane];
            float w1 = sWt[(k4 * 4 + 1) * OUTD + lane];
            float w2 = sWt[(k4 * 4 + 2) * OUTD + lane];
            float w3 = sWt[(k4 * 4 + 3) * OUTD + lane];
            float4 x0 = xr0[k4], x1 = xr1[k4], x2 = xr2[k4], x3 = xr3[k4];
            acc0 += x0.x * w0 + x0.y * w1 + x0.z * w2 + x0.w * w3;
            acc1 += x1.x * w0 + x1.y * w1 + x1.z * w2 + x1.w * w3;
            acc2 += x2.x * w0 + x2.y * w1 + x2.z * w2 + x2.w * w3;
            acc3 += x3.x * w0 + x3.y * w1 + x3.z * w2 + x3.w * w3;
        }
    }
    float as = att_s[lane];
    float ad = att_d[lane];
    float accs[4] = {acc0, acc1, acc2, acc3};
#pragma unroll
    for (int rr = 0; rr < 4; rr++) {
        long long row = rowBase + wave * 4 + rr;
        if (row >= NN) continue;
        Wh[row * OUTD + lane] = accs[rr];
        float vs = accs[rr] * as, vd = accs[rr] * ad;
#pragma unroll
        for (int m = 1; m < 16; m <<= 1) {
            vs += __shfl_xor(vs, m);
            vd += __shfl_xor(vd, m);
        }
        if ((lane & 15) == 0) {
            int h = lane >> 4;
            asrc[row * NH + h] = vs;
            adst[row * NH + h] = vd;
        }
    }
}

// ---------------- degree histogram (4 edges/thread) ----------------
__global__ void k_hist(const int* __restrict__ ei, int* __restrict__ deg) {
    int i = blockIdx.x * 256 + threadIdx.x;
    if (i < NE / 4) {
        int4 dv = ((const int4*)(ei + NE))[i];
        atomicAdd(&deg[dv.x], 1);
        atomicAdd(&deg[dv.y], 1);
        atomicAdd(&deg[dv.z], 1);
        atomicAdd(&deg[dv.w], 1);
    }
}

// ---------------- 3-phase exclusive scan over deg[NN] ----------------
__global__ __launch_bounds__(256) void k_scan1(const int* __restrict__ deg,
                                               int* __restrict__ offA,
                                               int* __restrict__ bsum) {
    __shared__ int sd[256];
    int b = blockIdx.x, t = threadIdx.x;
    int base = b * 1024 + t * 4;
    int v0 = 0, v1 = 0, v2 = 0, v3 = 0;
    if (base + 0 < NN) v0 = deg[base + 0];
    if (base + 1 < NN) v1 = deg[base + 1];
    if (base + 2 < NN) v2 = deg[base + 2];
    if (base + 3 < NN) v3 = deg[base + 3];
    int s = v0 + v1 + v2 + v3;
    sd[t] = s;
    __syncthreads();
    for (int ofs = 1; ofs < 256; ofs <<= 1) {
        int xv = 0;
        if (t >= ofs) xv = sd[t - ofs];
        __syncthreads();
        sd[t] += xv;
        __syncthreads();
    }
    int excl = sd[t] - s;
    if (base + 0 < NN) offA[base + 0] = excl;
    if (base + 1 < NN) offA[base + 1] = excl + v0;
    if (base + 2 < NN) offA[base + 2] = excl + v0 + v1;
    if (base + 3 < NN) offA[base + 3] = excl + v0 + v1 + v2;
    if (t == 255) bsum[b] = sd[255];
}

__global__ __launch_bounds__(128) void k_scan2(int* __restrict__ bsum) {
    __shared__ int sd[128];
    int t = threadIdx.x;
    int v = (t < NB1) ? bsum[t] : 0;
    sd[t] = v;
    __syncthreads();
    for (int ofs = 1; ofs < 128; ofs <<= 1) {
        int xv = 0;
        if (t >= ofs) xv = sd[t - ofs];
        __syncthreads();
        sd[t] += xv;
        __syncthreads();
    }
    if (t < NB1) bsum[t] = sd[t] - v;  // exclusive
}

__global__ void k_scan3(const int* __restrict__ offA, const int* __restrict__ bsum,
                        int* __restrict__ off, int* __restrict__ pos) {
    int i = blockIdx.x * 256 + threadIdx.x;
    if (i < NN) {
        int v = offA[i] + bsum[i >> 10];
        off[i] = v;
        pos[i] = v;
    }
    if (i == 0) off[NN] = NE;
}

// ---------------- edge scores -> exp, packed 16B CSR scatter ----------
// record @ rec + 4*p floats: [ex0 ex1 ex2 ex3] with src's 17 bits packed
// into the low mantissa bits (5+4+4+4) — rel. error <= ~4e-6, invisible.
// 1 edge/thread: max wave concurrency for the latency-bound atomic+scatter
// (round-2 post-mortem: 4-edge batch halved occupancy 60->42, dur +25%).
__global__ __launch_bounds__(256) void k_edge(
        const int* __restrict__ ei, const float* __restrict__ ea,
        const float* __restrict__ We, const float* __restrict__ asrc,
        const float* __restrict__ adst, int* __restrict__ pos,
        float* __restrict__ rec) {
    __shared__ float sWe[NH * ED];
    if (threadIdx.x < NH * ED) sWe[threadIdx.x] = We[threadIdx.x];
    __syncthreads();
    int e = blockIdx.x * 256 + threadIdx.x;
    if (e >= NE) return;
    int s = ei[e];
    int d = ei[NE + e];
    int p = atomicAdd(&pos[d], 1);          // issue first: longest latency
    float4 as4 = *(const float4*)(asrc + (long long)s * NH);
    float4 ad4 = *(const float4*)(adst + (long long)d * NH);
    f4v* ea4 = (f4v*)(const_cast<float*>(ea) + (long long)e * ED);
    f4v q0 = __builtin_nontemporal_load(ea4 + 0);
    f4v q1 = __builtin_nontemporal_load(ea4 + 1);
    f4v q2 = __builtin_nontemporal_load(ea4 + 2);
    f4v q3 = __builtin_nontemporal_load(ea4 + 3);
    float asv[4] = {as4.x, as4.y, as4.z, as4.w};
    float adv[4] = {ad4.x, ad4.y, ad4.z, ad4.w};
    unsigned int u[4];
#pragma unroll
    for (int h = 0; h < NH; h++) {
        const float* w = sWe + h * ED;
        float t = asv[h] + adv[h];
        t += q0.x * w[0]  + q0.y * w[1]  + q0.z * w[2]  + q0.w * w[3];
        t += q1.x * w[4]  + q1.y * w[5]  + q1.z * w[6]  + q1.w * w[7];
        t += q2.x * w[8]  + q2.y * w[9]  + q2.z * w[10] + q2.w * w[11];
        t += q3.x * w[12] + q3.y * w[13] + q3.z * w[14] + q3.w * w[15];
        t = (t >= 0.f) ? t : 0.2f * t;
        u[h] = __float_as_uint(expf(t));   // max score ~ +15 -> exp ~ 3e6, safe in f32
    }
    unsigned int ss = (unsigned int)s;
    u[0] = (u[0] & ~31u) | (ss & 31u);
    u[1] = (u[1] & ~15u) | ((ss >> 5) & 15u);
    u[2] = (u[2] & ~15u) | ((ss >> 9) & 15u);
    u[3] = (u[3] & ~15u) | ((ss >> 13) & 15u);
    f4v rv = {__uint_as_float(u[0]), __uint_as_float(u[1]),
              __uint_as_float(u[2]), __uint_as_float(u[3])};
    __builtin_nontemporal_store(rv, (f4v*)rec + p);
}

// ---------------- gather: normalize + accumulate + elu --------------
// wave per node; 4 groups of 16 lanes; group g handles edges j = start+g, +4...
// lane holds channels c16*4..c16*4+3 (float4); head h = c16>>2.
// no expf here: records already hold exp(score); src decoded from mantissa bits
__global__ __launch_bounds__(256) void k_gather(
        const int* __restrict__ off, float* __restrict__ rec,
        const float* __restrict__ Wh, const float* __restrict__ bias,
        float* __restrict__ out) {
    int node = blockIdx.x * 4 + (threadIdx.x >> 6);
    int lane = threadIdx.x & 63;
    if (node >= NN) return;
    int start = off[node], end = off[node + 1];
    int g = lane >> 4;       // edge group
    int c16 = lane & 15;     // channel quad
    int h = c16 >> 2;        // head

    float accx = 0.f, accy = 0.f, accz = 0.f, accw = 0.f;
    float dsum = 0.f;
#pragma unroll 2
    for (int j = start + g; j < end; j += 4) {
        f4v r = __builtin_nontemporal_load((f4v*)rec + j);   // 16-lane broadcast
        unsigned int b0 = __float_as_uint(r.x), b1 = __float_as_uint(r.y);
        unsigned int b2 = __float_as_uint(r.z), b3 = __float_as_uint(r.w);
        int src = (int)((b0 & 31u) | ((b1 & 15u) << 5) | ((b2 & 15u) << 9) | ((b3 & 15u) << 13));
        float ex = (h == 0) ? r.x : (h == 1) ? r.y : (h == 2) ? r.z : r.w;
        float4 w = *(const float4*)(Wh + (long long)src * OUTD + c16 * 4);
        accx += ex * w.x;
        accy += ex * w.y;
        accz += ex * w.z;
        accw += ex * w.w;
        dsum += ex;
    }
    // combine the 4 edge-groups (lanes l, l+16, l+32, l+48 share c16)
#pragma unroll
    for (int m = 16; m < 64; m <<= 1) {
        accx += __shfl_xor(accx, m);
        accy += __shfl_xor(accy, m);
        accz += __shfl_xor(accz, m);
        accw += __shfl_xor(accw, m);
        dsum += __shfl_xor(dsum, m);
    }
    if (g == 0) {
        float rden = 1.0f / (dsum + 1e-9f);
        const float4 b4 = *(const float4*)(bias + c16 * 4);
        float vx = accx * rden + b4.x;
        float vy = accy * rden + b4.y;
        float vz = accz * rden + b4.z;
        float vw = accw * rden + b4.w;
        vx = (vx > 0.f) ? vx : expm1f(vx);
        vy = (vy > 0.f) ? vy : expm1f(vy);
        vz = (vz > 0.f) ? vz : expm1f(vz);
        vw = (vw > 0.f) ? vw : expm1f(vw);
        f4v v = {vx, vy, vz, vw};
        __builtin_nontemporal_store(v, (f4v*)(out + (long long)node * OUTD) + c16);
    }
}

extern "C" void kernel_launch(void* const* d_in, const int* in_sizes, int n_in,
                              void* d_out, int out_size, void* d_ws, size_t ws_size,
                              hipStream_t stream) {
    const float* x     = (const float*)d_in[0];   // [NN,128]
    const int*   ei    = (const int*)d_in[1];     // [2,NE]
    const float* ea    = (const float*)d_in[2];   // [NE,16]
    const float* Wn    = (const float*)d_in[3];   // [64,128]
    const float* We    = (const float*)d_in[4];   // [4,16]
    const float* att_s = (const float*)d_in[5];   // 64
    const float* att_d = (const float*)d_in[6];   // 64
    const float* bias  = (const float*)d_in[7];   // 64
    float* out = (float*)d_out;

    float* ws   = (float*)d_ws;
    float* Wh   = ws;                                   // NN*64 f
    float* asrc = Wh + (size_t)NN * OUTD;               // NN*4 f
    float* adst = asrc + (size_t)NN * NH;               // NN*4 f
    float* rec  = adst + (size_t)NN * NH;               // NE*4 f (packed 16B records)
    int*   deg  = (int*)(rec + (size_t)NE * 4);         // NN i
    int*   offA = deg + NN;                             // NN i
    int*   off  = offA + NN;                            // NN+1 i
    int*   pos  = off + NN + 1;                         // NN i
    int*   bsum = pos + NN;                             // 128 i

    k_node<<<(NN + 15) / 16, 256, 0, stream>>>(x, Wn, att_s, att_d, Wh, asrc, adst, deg);
    k_hist<<<(NE / 4 + 255) / 256, 256, 0, stream>>>(ei, deg);
    k_scan1<<<NB1, 256, 0, stream>>>(deg, offA, bsum);
    k_scan2<<<1, 128, 0, stream>>>(bsum);
    k_scan3<<<(NN + 255) / 256, 256, 0, stream>>>(offA, bsum, off, pos);
    k_edge<<<(NE + 255) / 256, 256, 0, stream>>>(ei, ea, We, asrc, adst, pos, rec);
    k_gather<<<(NN + 3) / 4, 256, 0, stream>>>(off, rec, Wh, bias, out);
}

// Round 4
// 428.949 us; speedup vs baseline: 1.5471x; 1.1258x over previous
//
#include <hip/hip_runtime.h>
#include <math.h>

#define NN 100000
#define NE 1600000
#define IND 128
#define OUTD 64
#define ED 16
#define NH 4
#define HD 16
#define NB1 98      // ceil(NN/1024) for scan phase 1

typedef float f4v __attribute__((ext_vector_type(4)));

// ---------------- zero degree histogram ----------------
__global__ void k_zero(int* __restrict__ deg) {
    int i = blockIdx.x * 256 + threadIdx.x;
    if (i < NN) deg[i] = 0;
}

// ---------------- node GEMM + attention scalars + fused edge histogram ----
// 6250 blocks == NE/256: each block also ranks 256 edges (atomicAdd deg) —
// the atomic latency hides under the GEMM. k_edge then needs NO atomics.
__global__ __launch_bounds__(256) void k_node(
        const float* __restrict__ x, const float* __restrict__ Wn,
        const float* __restrict__ att_s, const float* __restrict__ att_d,
        float* __restrict__ Wh, float* __restrict__ asrc, float* __restrict__ adst,
        const int* __restrict__ ei, int* __restrict__ deg, int* __restrict__ rnk) {
    __shared__ float sWt[IND * OUTD];   // 32 KB, [k][c]
    __shared__ float sx[16][IND];       // 8 KB
    int tid = threadIdx.x;
    long long rowBase = (long long)blockIdx.x * 16;

    // fused histogram: this block's 256 edges
    int e = blockIdx.x * 256 + tid;     // grid is exactly NE/256 blocks
    int dd = ei[NE + e];

    {
        int c = tid & 63;
        for (int k4 = tid >> 6; k4 < IND / 4; k4 += 4) {
            float4 v = ((const float4*)Wn)[c * (IND / 4) + k4];
            sWt[(k4 * 4 + 0) * OUTD + c] = v.x;
            sWt[(k4 * 4 + 1) * OUTD + c] = v.y;
            sWt[(k4 * 4 + 2) * OUTD + c] = v.z;
            sWt[(k4 * 4 + 3) * OUTD + c] = v.w;
        }
    }
    for (int i = tid; i < 16 * (IND / 4); i += 256) {
        int r = i >> 5, k4 = i & 31;
        long long row = rowBase + r;
        float4 v = make_float4(0.f, 0.f, 0.f, 0.f);
        if (row < NN) v = ((const float4*)x)[row * (IND / 4) + k4];
        ((float4*)sx)[r * (IND / 4) + k4] = v;
    }

    // issue the atomic while LDS staging / GEMM keeps the wave busy
    rnk[e] = atomicAdd(&deg[dd], 1);

    __syncthreads();

    int wave = tid >> 6, lane = tid & 63;
    float acc0 = 0.f, acc1 = 0.f, acc2 = 0.f, acc3 = 0.f;
    const float4* xr0 = (const float4*)&sx[wave * 4 + 0][0];
    const float4* xr1 = (const float4*)&sx[wave * 4 + 1][0];
    const float4* xr2 = (const float4*)&sx[wave * 4 + 2][0];
    const float4* xr3 = (const float4*)&sx[wave * 4 + 3][0];
#pragma unroll 1
    for (int kk = 0; kk < IND / 16; kk++) {
#pragma unroll
        for (int j = 0; j < 4; j++) {
            int k4 = kk * 4 + j;
            float w0 = sWt[(k4 * 4 + 0) * OUTD + lane];
            float w1 = sWt[(k4 * 4 + 1) * OUTD + lane];
            float w2 = sWt[(k4 * 4 + 2) * OUTD + lane];
            float w3 = sWt[(k4 * 4 + 3) * OUTD + lane];
            float4 x0 = xr0[k4], x1 = xr1[k4], x2 = xr2[k4], x3 = xr3[k4];
            acc0 += x0.x * w0 + x0.y * w1 + x0.z * w2 + x0.w * w3;
            acc1 += x1.x * w0 + x1.y * w1 + x1.z * w2 + x1.w * w3;
            acc2 += x2.x * w0 + x2.y * w1 + x2.z * w2 + x2.w * w3;
            acc3 += x3.x * w0 + x3.y * w1 + x3.z * w2 + x3.w * w3;
        }
    }
    float as = att_s[lane];
    float ad = att_d[lane];
    float accs[4] = {acc0, acc1, acc2, acc3};
#pragma unroll
    for (int rr = 0; rr < 4; rr++) {
        long long row = rowBase + wave * 4 + rr;
        if (row >= NN) continue;
        Wh[row * OUTD + lane] = accs[rr];
        float vs = accs[rr] * as, vd = accs[rr] * ad;
#pragma unroll
        for (int m = 1; m < 16; m <<= 1) {
            vs += __shfl_xor(vs, m);
            vd += __shfl_xor(vd, m);
        }
        if ((lane & 15) == 0) {
            int h = lane >> 4;
            asrc[row * NH + h] = vs;
            adst[row * NH + h] = vd;
        }
    }
}

// ---------------- 3-phase exclusive scan over deg[NN] ----------------
__global__ __launch_bounds__(256) void k_scan1(const int* __restrict__ deg,
                                               int* __restrict__ offA,
                                               int* __restrict__ bsum) {
    __shared__ int sd[256];
    int b = blockIdx.x, t = threadIdx.x;
    int base = b * 1024 + t * 4;
    int v0 = 0, v1 = 0, v2 = 0, v3 = 0;
    if (base + 0 < NN) v0 = deg[base + 0];
    if (base + 1 < NN) v1 = deg[base + 1];
    if (base + 2 < NN) v2 = deg[base + 2];
    if (base + 3 < NN) v3 = deg[base + 3];
    int s = v0 + v1 + v2 + v3;
    sd[t] = s;
    __syncthreads();
    for (int ofs = 1; ofs < 256; ofs <<= 1) {
        int xv = 0;
        if (t >= ofs) xv = sd[t - ofs];
        __syncthreads();
        sd[t] += xv;
        __syncthreads();
    }
    int excl = sd[t] - s;
    if (base + 0 < NN) offA[base + 0] = excl;
    if (base + 1 < NN) offA[base + 1] = excl + v0;
    if (base + 2 < NN) offA[base + 2] = excl + v0 + v1;
    if (base + 3 < NN) offA[base + 3] = excl + v0 + v1 + v2;
    if (t == 255) bsum[b] = sd[255];
}

__global__ __launch_bounds__(128) void k_scan2(int* __restrict__ bsum) {
    __shared__ int sd[128];
    int t = threadIdx.x;
    int v = (t < NB1) ? bsum[t] : 0;
    sd[t] = v;
    __syncthreads();
    for (int ofs = 1; ofs < 128; ofs <<= 1) {
        int xv = 0;
        if (t >= ofs) xv = sd[t - ofs];
        __syncthreads();
        sd[t] += xv;
        __syncthreads();
    }
    if (t < NB1) bsum[t] = sd[t] - v;  // exclusive
}

__global__ void k_scan3(const int* __restrict__ offA, const int* __restrict__ bsum,
                        int* __restrict__ off) {
    int i = blockIdx.x * 256 + threadIdx.x;
    if (i < NN) off[i] = offA[i] + bsum[i >> 10];
    if (i == 0) off[NN] = NE;
}

// ---------------- edge scores -> exp, packed 16B CSR scatter ----------
// record @ rec + 4*p floats: [ex0 ex1 ex2 ex3] with src's 17 bits packed
// into the low mantissa bits (5+4+4+4) — rel. error <= ~4e-6, invisible.
// NO atomics: p = off[d] + rnk[e] (rank precomputed in k_node's fused hist).
__global__ __launch_bounds__(256) void k_edge(
        const int* __restrict__ ei, const float* __restrict__ ea,
        const float* __restrict__ We, const float* __restrict__ asrc,
        const float* __restrict__ adst, const int* __restrict__ off,
        const int* __restrict__ rnk, float* __restrict__ rec) {
    __shared__ float sWe[NH * ED];
    if (threadIdx.x < NH * ED) sWe[threadIdx.x] = We[threadIdx.x];
    __syncthreads();
    int e = blockIdx.x * 256 + threadIdx.x;   // grid == NE/256 exactly
    int s = ei[e];
    int d = ei[NE + e];
    int r = rnk[e];
    float4 as4 = *(const float4*)(asrc + (long long)s * NH);
    float4 ad4 = *(const float4*)(adst + (long long)d * NH);
    int p = off[d] + r;     // off: 400KB, hot in L2
    f4v* ea4 = (f4v*)(const_cast<float*>(ea) + (long long)e * ED);
    f4v q0 = __builtin_nontemporal_load(ea4 + 0);
    f4v q1 = __builtin_nontemporal_load(ea4 + 1);
    f4v q2 = __builtin_nontemporal_load(ea4 + 2);
    f4v q3 = __builtin_nontemporal_load(ea4 + 3);
    float asv[4] = {as4.x, as4.y, as4.z, as4.w};
    float adv[4] = {ad4.x, ad4.y, ad4.z, ad4.w};
    unsigned int u[4];
#pragma unroll
    for (int h = 0; h < NH; h++) {
        const float* w = sWe + h * ED;
        float t = asv[h] + adv[h];
        t += q0.x * w[0]  + q0.y * w[1]  + q0.z * w[2]  + q0.w * w[3];
        t += q1.x * w[4]  + q1.y * w[5]  + q1.z * w[6]  + q1.w * w[7];
        t += q2.x * w[8]  + q2.y * w[9]  + q2.z * w[10] + q2.w * w[11];
        t += q3.x * w[12] + q3.y * w[13] + q3.z * w[14] + q3.w * w[15];
        t = (t >= 0.f) ? t : 0.2f * t;
        u[h] = __float_as_uint(expf(t));   // max score ~ +15 -> exp ~ 3e6, safe in f32
    }
    unsigned int ss = (unsigned int)s;
    u[0] = (u[0] & ~31u) | (ss & 31u);
    u[1] = (u[1] & ~15u) | ((ss >> 5) & 15u);
    u[2] = (u[2] & ~15u) | ((ss >> 9) & 15u);
    u[3] = (u[3] & ~15u) | ((ss >> 13) & 15u);
    f4v rv = {__uint_as_float(u[0]), __uint_as_float(u[1]),
              __uint_as_float(u[2]), __uint_as_float(u[3])};
    __builtin_nontemporal_store(rv, (f4v*)rec + p);
}

// ---------------- gather: normalize + accumulate + elu --------------
// wave per node; 4 groups of 16 lanes; group g handles edges j = start+g, +4...
// lane holds channels c16*4..c16*4+3 (float4); head h = c16>>2.
// no expf here: records already hold exp(score); src decoded from mantissa bits
__global__ __launch_bounds__(256) void k_gather(
        const int* __restrict__ off, float* __restrict__ rec,
        const float* __restrict__ Wh, const float* __restrict__ bias,
        float* __restrict__ out) {
    int node = blockIdx.x * 4 + (threadIdx.x >> 6);
    int lane = threadIdx.x & 63;
    if (node >= NN) return;
    int start = off[node], end = off[node + 1];
    int g = lane >> 4;       // edge group
    int c16 = lane & 15;     // channel quad
    int h = c16 >> 2;        // head

    float accx = 0.f, accy = 0.f, accz = 0.f, accw = 0.f;
    float dsum = 0.f;
#pragma unroll 2
    for (int j = start + g; j < end; j += 4) {
        f4v r = __builtin_nontemporal_load((f4v*)rec + j);   // 16-lane broadcast
        unsigned int b0 = __float_as_uint(r.x), b1 = __float_as_uint(r.y);
        unsigned int b2 = __float_as_uint(r.z), b3 = __float_as_uint(r.w);
        int src = (int)((b0 & 31u) | ((b1 & 15u) << 5) | ((b2 & 15u) << 9) | ((b3 & 15u) << 13));
        float ex = (h == 0) ? r.x : (h == 1) ? r.y : (h == 2) ? r.z : r.w;
        float4 w = *(const float4*)(Wh + (long long)src * OUTD + c16 * 4);
        accx += ex * w.x;
        accy += ex * w.y;
        accz += ex * w.z;
        accw += ex * w.w;
        dsum += ex;
    }
    // combine the 4 edge-groups (lanes l, l+16, l+32, l+48 share c16)
#pragma unroll
    for (int m = 16; m < 64; m <<= 1) {
        accx += __shfl_xor(accx, m);
        accy += __shfl_xor(accy, m);
        accz += __shfl_xor(accz, m);
        accw += __shfl_xor(accw, m);
        dsum += __shfl_xor(dsum, m);
    }
    if (g == 0) {
        float rden = 1.0f / (dsum + 1e-9f);
        const float4 b4 = *(const float4*)(bias + c16 * 4);
        float vx = accx * rden + b4.x;
        float vy = accy * rden + b4.y;
        float vz = accz * rden + b4.z;
        float vw = accw * rden + b4.w;
        vx = (vx > 0.f) ? vx : expm1f(vx);
        vy = (vy > 0.f) ? vy : expm1f(vy);
        vz = (vz > 0.f) ? vz : expm1f(vz);
        vw = (vw > 0.f) ? vw : expm1f(vw);
        f4v v = {vx, vy, vz, vw};
        __builtin_nontemporal_store(v, (f4v*)(out + (long long)node * OUTD) + c16);
    }
}

extern "C" void kernel_launch(void* const* d_in, const int* in_sizes, int n_in,
                              void* d_out, int out_size, void* d_ws, size_t ws_size,
                              hipStream_t stream) {
    const float* x     = (const float*)d_in[0];   // [NN,128]
    const int*   ei    = (const int*)d_in[1];     // [2,NE]
    const float* ea    = (const float*)d_in[2];   // [NE,16]
    const float* Wn    = (const float*)d_in[3];   // [64,128]
    const float* We    = (const float*)d_in[4];   // [4,16]
    const float* att_s = (const float*)d_in[5];   // 64
    const float* att_d = (const float*)d_in[6];   // 64
    const float* bias  = (const float*)d_in[7];   // 64
    float* out = (float*)d_out;

    float* ws   = (float*)d_ws;
    float* Wh   = ws;                                   // NN*64 f
    float* asrc = Wh + (size_t)NN * OUTD;               // NN*4 f
    float* adst = asrc + (size_t)NN * NH;               // NN*4 f
    float* rec  = adst + (size_t)NN * NH;               // NE*4 f (packed 16B records)
    int*   deg  = (int*)(rec + (size_t)NE * 4);         // NN i
    int*   offA = deg + NN;                             // NN i
    int*   off  = offA + NN;                            // NN+1 i
    int*   bsum = off + NN + 1;                         // 128 i
    int*   rnk  = bsum + 128;                           // NE i

    k_zero<<<(NN + 255) / 256, 256, 0, stream>>>(deg);
    k_node<<<(NN + 15) / 16, 256, 0, stream>>>(x, Wn, att_s, att_d, Wh, asrc, adst,
                                               ei, deg, rnk);
    k_scan1<<<NB1, 256, 0, stream>>>(deg, offA, bsum);
    k_scan2<<<1, 128, 0, stream>>>(bsum);
    k_scan3<<<(NN + 255) / 256, 256, 0, stream>>>(offA, bsum, off);
    k_edge<<<(NE + 255) / 256, 256, 0, stream>>>(ei, ea, We, asrc, adst, off, rnk, rec);
    k_gather<<<(NN + 3) / 4, 256, 0, stream>>>(off, rec, Wh, bias, out);
}

// Round 5
// 421.145 us; speedup vs baseline: 1.5758x; 1.0185x over previous
//
#include <hip/hip_runtime.h>
#include <math.h>

#define NN 100000
#define NE 1600000
#define IND 128
#define OUTD 64
#define ED 16
#define NH 4
#define HD 16
#define NB1 98      // ceil(NN/1024) for scan phase 1

typedef float f4v __attribute__((ext_vector_type(4)));

// ---------------- zero degree histogram ----------------
__global__ void k_zero(int* __restrict__ deg) {
    int i = blockIdx.x * 256 + threadIdx.x;
    if (i < NN) deg[i] = 0;
}

// ---------------- node GEMM + attention scalars + fused edge histogram ----
// 6250 blocks == NE/256 == NN/16. W kept in native [c][k] layout with a
// float4 XOR swizzle (k4 ^ (c&7)): per-lane W read is ONE ds_read_b128,
// conflict-free (the XOR spreads lanes over all 32 banks).
// hist atomic moved to the kernel TAIL: nothing waits on it (round-4
// post-mortem: atomic+rnk before __syncthreads stalled every wave on the
// vmcnt(0) barrier drain).
__global__ __launch_bounds__(256) void k_node(
        const float* __restrict__ x, const float* __restrict__ Wn,
        const float* __restrict__ att_s, const float* __restrict__ att_d,
        float* __restrict__ Wh, float* __restrict__ asrc, float* __restrict__ adst,
        const int* __restrict__ ei, int* __restrict__ deg, int* __restrict__ rnk) {
    __shared__ float4 sWc[64 * 32];     // 32 KB, [c][k4 ^ (c&7)]
    __shared__ float sx[16][IND];       // 8 KB
    int tid = threadIdx.x;
    long long rowBase = (long long)blockIdx.x * 16;

    // fused histogram edge: issue the d-index load now, use at kernel tail
    int e = blockIdx.x * 256 + tid;     // grid is exactly NE/256 blocks
    int dd = ei[NE + e];

    // stage Wn: native row-major copy with float4 XOR swizzle
#pragma unroll
    for (int j = 0; j < 8; j++) {
        int i = tid + j * 256;          // i in [0, 2048): c = i>>5, k4 = i&31
        int c = i >> 5, k4 = i & 31;
        sWc[c * 32 + (k4 ^ (c & 7))] = ((const float4*)Wn)[i];
    }
    for (int i = tid; i < 16 * (IND / 4); i += 256) {
        int r = i >> 5, k4 = i & 31;
        long long row = rowBase + r;
        float4 v = make_float4(0.f, 0.f, 0.f, 0.f);
        if (row < NN) v = ((const float4*)x)[row * (IND / 4) + k4];
        ((float4*)sx)[r * (IND / 4) + k4] = v;
    }
    __syncthreads();

    int wave = tid >> 6, lane = tid & 63;
    float acc0 = 0.f, acc1 = 0.f, acc2 = 0.f, acc3 = 0.f;
    const float4* xr0 = (const float4*)&sx[wave * 4 + 0][0];
    const float4* xr1 = (const float4*)&sx[wave * 4 + 1][0];
    const float4* xr2 = (const float4*)&sx[wave * 4 + 2][0];
    const float4* xr3 = (const float4*)&sx[wave * 4 + 3][0];
    const float4* wrow = &sWc[lane * 32];
    int lx = lane & 7;
#pragma unroll 1
    for (int kk = 0; kk < IND / 16; kk++) {
#pragma unroll
        for (int j = 0; j < 4; j++) {
            int k4 = kk * 4 + j;
            float4 w4 = wrow[k4 ^ lx];
            float4 x0 = xr0[k4], x1 = xr1[k4], x2 = xr2[k4], x3 = xr3[k4];
            acc0 += x0.x * w4.x + x0.y * w4.y + x0.z * w4.z + x0.w * w4.w;
            acc1 += x1.x * w4.x + x1.y * w4.y + x1.z * w4.z + x1.w * w4.w;
            acc2 += x2.x * w4.x + x2.y * w4.y + x2.z * w4.z + x2.w * w4.w;
            acc3 += x3.x * w4.x + x3.y * w4.y + x3.z * w4.z + x3.w * w4.w;
        }
    }
    float as = att_s[lane];
    float ad = att_d[lane];
    float accs[4] = {acc0, acc1, acc2, acc3};
#pragma unroll
    for (int rr = 0; rr < 4; rr++) {
        long long row = rowBase + wave * 4 + rr;
        if (row >= NN) continue;
        Wh[row * OUTD + lane] = accs[rr];
        float vs = accs[rr] * as, vd = accs[rr] * ad;
#pragma unroll
        for (int m = 1; m < 16; m <<= 1) {
            vs += __shfl_xor(vs, m);
            vd += __shfl_xor(vd, m);
        }
        if ((lane & 15) == 0) {
            int h = lane >> 4;
            asrc[row * NH + h] = vs;
            adst[row * NH + h] = vd;
        }
    }
    // tail: histogram atomic + rank store — nothing downstream waits on this
    rnk[e] = atomicAdd(&deg[dd], 1);
}

// ---------------- 3-phase exclusive scan over deg[NN] ----------------
__global__ __launch_bounds__(256) void k_scan1(const int* __restrict__ deg,
                                               int* __restrict__ offA,
                                               int* __restrict__ bsum) {
    __shared__ int sd[256];
    int b = blockIdx.x, t = threadIdx.x;
    int base = b * 1024 + t * 4;
    int v0 = 0, v1 = 0, v2 = 0, v3 = 0;
    if (base + 0 < NN) v0 = deg[base + 0];
    if (base + 1 < NN) v1 = deg[base + 1];
    if (base + 2 < NN) v2 = deg[base + 2];
    if (base + 3 < NN) v3 = deg[base + 3];
    int s = v0 + v1 + v2 + v3;
    sd[t] = s;
    __syncthreads();
    for (int ofs = 1; ofs < 256; ofs <<= 1) {
        int xv = 0;
        if (t >= ofs) xv = sd[t - ofs];
        __syncthreads();
        sd[t] += xv;
        __syncthreads();
    }
    int excl = sd[t] - s;
    if (base + 0 < NN) offA[base + 0] = excl;
    if (base + 1 < NN) offA[base + 1] = excl + v0;
    if (base + 2 < NN) offA[base + 2] = excl + v0 + v1;
    if (base + 3 < NN) offA[base + 3] = excl + v0 + v1 + v2;
    if (t == 255) bsum[b] = sd[255];
}

__global__ __launch_bounds__(128) void k_scan2(int* __restrict__ bsum) {
    __shared__ int sd[128];
    int t = threadIdx.x;
    int v = (t < NB1) ? bsum[t] : 0;
    sd[t] = v;
    __syncthreads();
    for (int ofs = 1; ofs < 128; ofs <<= 1) {
        int xv = 0;
        if (t >= ofs) xv = sd[t - ofs];
        __syncthreads();
        sd[t] += xv;
        __syncthreads();
    }
    if (t < NB1) bsum[t] = sd[t] - v;  // exclusive
}

__global__ void k_scan3(const int* __restrict__ offA, const int* __restrict__ bsum,
                        int* __restrict__ off) {
    int i = blockIdx.x * 256 + threadIdx.x;
    if (i < NN) off[i] = offA[i] + bsum[i >> 10];
    if (i == 0) off[NN] = NE;
}

// ---------------- edge scores -> exp, packed 16B CSR scatter ----------
// record @ rec + 4*p floats: [ex0 ex1 ex2 ex3] with src's 17 bits packed
// into the low mantissa bits (5+4+4+4) — rel. error <= ~4e-6, invisible.
// NO atomics: p = off[d] + rnk[e] (rank precomputed in k_node's fused hist).
__global__ __launch_bounds__(256) void k_edge(
        const int* __restrict__ ei, const float* __restrict__ ea,
        const float* __restrict__ We, const float* __restrict__ asrc,
        const float* __restrict__ adst, const int* __restrict__ off,
        const int* __restrict__ rnk, float* __restrict__ rec) {
    __shared__ float sWe[NH * ED];
    if (threadIdx.x < NH * ED) sWe[threadIdx.x] = We[threadIdx.x];
    __syncthreads();
    int e = blockIdx.x * 256 + threadIdx.x;   // grid == NE/256 exactly
    int s = ei[e];
    int d = ei[NE + e];
    int r = rnk[e];
    float4 as4 = *(const float4*)(asrc + (long long)s * NH);
    float4 ad4 = *(const float4*)(adst + (long long)d * NH);
    int p = off[d] + r;     // off: 400KB, hot in L2
    f4v* ea4 = (f4v*)(const_cast<float*>(ea) + (long long)e * ED);
    f4v q0 = __builtin_nontemporal_load(ea4 + 0);
    f4v q1 = __builtin_nontemporal_load(ea4 + 1);
    f4v q2 = __builtin_nontemporal_load(ea4 + 2);
    f4v q3 = __builtin_nontemporal_load(ea4 + 3);
    float asv[4] = {as4.x, as4.y, as4.z, as4.w};
    float adv[4] = {ad4.x, ad4.y, ad4.z, ad4.w};
    unsigned int u[4];
#pragma unroll
    for (int h = 0; h < NH; h++) {
        const float* w = sWe + h * ED;
        float t = asv[h] + adv[h];
        t += q0.x * w[0]  + q0.y * w[1]  + q0.z * w[2]  + q0.w * w[3];
        t += q1.x * w[4]  + q1.y * w[5]  + q1.z * w[6]  + q1.w * w[7];
        t += q2.x * w[8]  + q2.y * w[9]  + q2.z * w[10] + q2.w * w[11];
        t += q3.x * w[12] + q3.y * w[13] + q3.z * w[14] + q3.w * w[15];
        t = (t >= 0.f) ? t : 0.2f * t;
        u[h] = __float_as_uint(expf(t));   // max score ~ +15 -> exp ~ 3e6, safe in f32
    }
    unsigned int ss = (unsigned int)s;
    u[0] = (u[0] & ~31u) | (ss & 31u);
    u[1] = (u[1] & ~15u) | ((ss >> 5) & 15u);
    u[2] = (u[2] & ~15u) | ((ss >> 9) & 15u);
    u[3] = (u[3] & ~15u) | ((ss >> 13) & 15u);
    f4v rv = {__uint_as_float(u[0]), __uint_as_float(u[1]),
              __uint_as_float(u[2]), __uint_as_float(u[3])};
    __builtin_nontemporal_store(rv, (f4v*)rec + p);
}

// ---------------- gather: normalize + accumulate + elu --------------
// wave per node; 4 groups of 16 lanes; group g handles edges j = start+g, +4...
// lane holds channels c16*4..c16*4+3 (float4); head h = c16>>2.
// no expf here: records already hold exp(score); src decoded from mantissa bits
__global__ __launch_bounds__(256) void k_gather(
        const int* __restrict__ off, float* __restrict__ rec,
        const float* __restrict__ Wh, const float* __restrict__ bias,
        float* __restrict__ out) {
    int node = blockIdx.x * 4 + (threadIdx.x >> 6);
    int lane = threadIdx.x & 63;
    if (node >= NN) return;
    int start = off[node], end = off[node + 1];
    int g = lane >> 4;       // edge group
    int c16 = lane & 15;     // channel quad
    int h = c16 >> 2;        // head

    float accx = 0.f, accy = 0.f, accz = 0.f, accw = 0.f;
    float dsum = 0.f;
#pragma unroll 2
    for (int j = start + g; j < end; j += 4) {
        f4v r = __builtin_nontemporal_load((f4v*)rec + j);   // 16-lane broadcast
        unsigned int b0 = __float_as_uint(r.x), b1 = __float_as_uint(r.y);
        unsigned int b2 = __float_as_uint(r.z), b3 = __float_as_uint(r.w);
        int src = (int)((b0 & 31u) | ((b1 & 15u) << 5) | ((b2 & 15u) << 9) | ((b3 & 15u) << 13));
        float ex = (h == 0) ? r.x : (h == 1) ? r.y : (h == 2) ? r.z : r.w;
        float4 w = *(const float4*)(Wh + (long long)src * OUTD + c16 * 4);
        accx += ex * w.x;
        accy += ex * w.y;
        accz += ex * w.z;
        accw += ex * w.w;
        dsum += ex;
    }
    // combine the 4 edge-groups (lanes l, l+16, l+32, l+48 share c16)
#pragma unroll
    for (int m = 16; m < 64; m <<= 1) {
        accx += __shfl_xor(accx, m);
        accy += __shfl_xor(accy, m);
        accz += __shfl_xor(accz, m);
        accw += __shfl_xor(accw, m);
        dsum += __shfl_xor(dsum, m);
    }
    if (g == 0) {
        float rden = 1.0f / (dsum + 1e-9f);
        const float4 b4 = *(const float4*)(bias + c16 * 4);
        float vx = accx * rden + b4.x;
        float vy = accy * rden + b4.y;
        float vz = accz * rden + b4.z;
        float vw = accw * rden + b4.w;
        vx = (vx > 0.f) ? vx : expm1f(vx);
        vy = (vy > 0.f) ? vy : expm1f(vy);
        vz = (vz > 0.f) ? vz : expm1f(vz);
        vw = (vw > 0.f) ? vw : expm1f(vw);
        f4v v = {vx, vy, vz, vw};
        __builtin_nontemporal_store(v, (f4v*)(out + (long long)node * OUTD) + c16);
    }
}

extern "C" void kernel_launch(void* const* d_in, const int* in_sizes, int n_in,
                              void* d_out, int out_size, void* d_ws, size_t ws_size,
                              hipStream_t stream) {
    const float* x     = (const float*)d_in[0];   // [NN,128]
    const int*   ei    = (const int*)d_in[1];     // [2,NE]
    const float* ea    = (const float*)d_in[2];   // [NE,16]
    const float* Wn    = (const float*)d_in[3];   // [64,128]
    const float* We    = (const float*)d_in[4];   // [4,16]
    const float* att_s = (const float*)d_in[5];   // 64
    const float* att_d = (const float*)d_in[6];   // 64
    const float* bias  = (const float*)d_in[7];   // 64
    float* out = (float*)d_out;

    float* ws   = (float*)d_ws;
    float* Wh   = ws;                                   // NN*64 f
    float* asrc = Wh + (size_t)NN * OUTD;               // NN*4 f
    float* adst = asrc + (size_t)NN * NH;               // NN*4 f
    float* rec  = adst + (size_t)NN * NH;               // NE*4 f (packed 16B records)
    int*   deg  = (int*)(rec + (size_t)NE * 4);         // NN i
    int*   offA = deg + NN;                             // NN i
    int*   off  = offA + NN;                            // NN+1 i
    int*   bsum = off + NN + 1;                         // 128 i
    int*   rnk  = bsum + 128;                           // NE i

    k_zero<<<(NN + 255) / 256, 256, 0, stream>>>(deg);
    k_node<<<(NN + 15) / 16, 256, 0, stream>>>(x, Wn, att_s, att_d, Wh, asrc, adst,
                                               ei, deg, rnk);
    k_scan1<<<NB1, 256, 0, stream>>>(deg, offA, bsum);
    k_scan2<<<1, 128, 0, stream>>>(bsum);
    k_scan3<<<(NN + 255) / 256, 256, 0, stream>>>(offA, bsum, off);
    k_edge<<<(NE + 255) / 256, 256, 0, stream>>>(ei, ea, We, asrc, adst, off, rnk, rec);
    k_gather<<<(NN + 3) / 4, 256, 0, stream>>>(off, rec, Wh, bias, out);
}

// Round 7
// 405.413 us; speedup vs baseline: 1.6369x; 1.0388x over previous
//
#include <hip/hip_runtime.h>
#include <math.h>

#define NN 100000
#define NE 1600000
#define IND 128
#define OUTD 64
#define ED 16
#define NH 4
#define HD 16
#define NB1 98      // ceil(NN/1024) for scan phase 1

typedef float f4v __attribute__((ext_vector_type(4)));

// ---------------- zero degree histogram ----------------
// plain kernel (NOT hipMemsetAsync: round-6 bench failed at container level;
// the memset inside kernel_launch was the only harness-interaction change)
__global__ void k_zero(int* __restrict__ deg) {
    int i = blockIdx.x * 256 + threadIdx.x;
    if (i < NN) deg[i] = 0;
}

// ---------------- node GEMM + attention scalars + fused edge histogram ----
// 3125 blocks x 512 threads == NE threads == NN/32 blocks.
// 32 rows/block, 8 waves, 4 rows/wave: W (32KB) amortized over 4 rows/wave,
// LDS 48KB -> 3 blocks/CU -> 24 waves/CU (75% cap; round-5 post-mortem: 40KB
// at 256 threads capped at 50% and measured 38%, latency-bound).
// W in native [c][k] layout, float4 XOR swizzle (k4 ^ (c&7)): one ds_read_b128
// per k4 (residual ~8-way quad alias costs ~4cy, still beats 4x ds_read_b32).
// hist atomic at kernel TAIL: nothing downstream in-kernel waits on it.
__global__ __launch_bounds__(512, 6) void k_node(
        const float* __restrict__ x, const float* __restrict__ Wn,
        const float* __restrict__ att_s, const float* __restrict__ att_d,
        float* __restrict__ Wh, float* __restrict__ asrc, float* __restrict__ adst,
        const int* __restrict__ ei, int* __restrict__ deg, int* __restrict__ rnk) {
    __shared__ float4 sWc[64 * 32];     // 32 KB, [c][k4 ^ (c&7)]
    __shared__ float sx[32][IND];       // 16 KB
    int tid = threadIdx.x;
    long long rowBase = (long long)blockIdx.x * 32;

    // fused histogram edge: issue the d-index load now, use at kernel tail
    int e = blockIdx.x * 512 + tid;     // grid is exactly NE/512 blocks
    int dd = ei[NE + e];

    // stage Wn: native row-major copy with float4 XOR swizzle (4 f4/thread)
#pragma unroll
    for (int j = 0; j < 4; j++) {
        int i = tid + j * 512;          // i in [0, 2048): c = i>>5, k4 = i&31
        int c = i >> 5, k4 = i & 31;
        sWc[c * 32 + (k4 ^ (c & 7))] = ((const float4*)Wn)[i];
    }
    // stage x rows (2 f4/thread); NN % 32 == 0 so no guards needed
#pragma unroll
    for (int j = 0; j < 2; j++) {
        int i = tid + j * 512;          // i in [0, 1024): r = i>>5, k4 = i&31
        int r = i >> 5, k4 = i & 31;
        ((float4*)sx)[r * 32 + k4] = ((const float4*)x)[(rowBase + r) * 32 + k4];
    }
    __syncthreads();

    int wave = tid >> 6, lane = tid & 63;   // wave 0..7, 4 rows each
    float acc0 = 0.f, acc1 = 0.f, acc2 = 0.f, acc3 = 0.f;
    const float4* xr0 = (const float4*)&sx[wave * 4 + 0][0];
    const float4* xr1 = (const float4*)&sx[wave * 4 + 1][0];
    const float4* xr2 = (const float4*)&sx[wave * 4 + 2][0];
    const float4* xr3 = (const float4*)&sx[wave * 4 + 3][0];
    const float4* wrow = &sWc[lane * 32];
    int lx = lane & 7;
#pragma unroll 1
    for (int kk = 0; kk < IND / 16; kk++) {
#pragma unroll
        for (int j = 0; j < 4; j++) {
            int k4 = kk * 4 + j;
            float4 w4 = wrow[k4 ^ lx];
            float4 x0 = xr0[k4], x1 = xr1[k4], x2 = xr2[k4], x3 = xr3[k4];
            acc0 += x0.x * w4.x + x0.y * w4.y + x0.z * w4.z + x0.w * w4.w;
            acc1 += x1.x * w4.x + x1.y * w4.y + x1.z * w4.z + x1.w * w4.w;
            acc2 += x2.x * w4.x + x2.y * w4.y + x2.z * w4.z + x2.w * w4.w;
            acc3 += x3.x * w4.x + x3.y * w4.y + x3.z * w4.z + x3.w * w4.w;
        }
    }
    float as = att_s[lane];
    float ad = att_d[lane];
    float accs[4] = {acc0, acc1, acc2, acc3};
#pragma unroll
    for (int rr = 0; rr < 4; rr++) {
        long long row = rowBase + wave * 4 + rr;
        Wh[row * OUTD + lane] = accs[rr];
        float vs = accs[rr] * as, vd = accs[rr] * ad;
#pragma unroll
        for (int m = 1; m < 16; m <<= 1) {
            vs += __shfl_xor(vs, m);
            vd += __shfl_xor(vd, m);
        }
        if ((lane & 15) == 0) {
            int h = lane >> 4;
            asrc[row * NH + h] = vs;
            adst[row * NH + h] = vd;
        }
    }
    // tail: histogram atomic + rank store — nothing downstream waits on this
    rnk[e] = atomicAdd(&deg[dd], 1);
}

// ---------------- 3-phase exclusive scan over deg[NN] ----------------
__global__ __launch_bounds__(256) void k_scan1(const int* __restrict__ deg,
                                               int* __restrict__ offA,
                                               int* __restrict__ bsum) {
    __shared__ int sd[256];
    int b = blockIdx.x, t = threadIdx.x;
    int base = b * 1024 + t * 4;
    int v0 = 0, v1 = 0, v2 = 0, v3 = 0;
    if (base + 0 < NN) v0 = deg[base + 0];
    if (base + 1 < NN) v1 = deg[base + 1];
    if (base + 2 < NN) v2 = deg[base + 2];
    if (base + 3 < NN) v3 = deg[base + 3];
    int s = v0 + v1 + v2 + v3;
    sd[t] = s;
    __syncthreads();
    for (int ofs = 1; ofs < 256; ofs <<= 1) {
        int xv = 0;
        if (t >= ofs) xv = sd[t - ofs];
        __syncthreads();
        sd[t] += xv;
        __syncthreads();
    }
    int excl = sd[t] - s;
    if (base + 0 < NN) offA[base + 0] = excl;
    if (base + 1 < NN) offA[base + 1] = excl + v0;
    if (base + 2 < NN) offA[base + 2] = excl + v0 + v1;
    if (base + 3 < NN) offA[base + 3] = excl + v0 + v1 + v2;
    if (t == 255) bsum[b] = sd[255];
}

__global__ __launch_bounds__(128) void k_scan2(int* __restrict__ bsum) {
    __shared__ int sd[128];
    int t = threadIdx.x;
    int v = (t < NB1) ? bsum[t] : 0;
    sd[t] = v;
    __syncthreads();
    for (int ofs = 1; ofs < 128; ofs <<= 1) {
        int xv = 0;
        if (t >= ofs) xv = sd[t - ofs];
        __syncthreads();
        sd[t] += xv;
        __syncthreads();
    }
    if (t < NB1) bsum[t] = sd[t] - v;  // exclusive
}

__global__ void k_scan3(const int* __restrict__ offA, const int* __restrict__ bsum,
                        int* __restrict__ off) {
    int i = blockIdx.x * 256 + threadIdx.x;
    if (i < NN) off[i] = offA[i] + bsum[i >> 10];
    if (i == 0) off[NN] = NE;
}

// ---------------- edge scores -> exp, packed 16B CSR scatter ----------
// record @ rec + 4*p floats: [ex0 ex1 ex2 ex3] with src's 17 bits packed
// into the low mantissa bits (5+4+4+4) — rel. error <= ~4e-6, invisible.
// NO atomics: p = off[d] + rnk[e] (rank precomputed in k_node's fused hist).
__global__ __launch_bounds__(256) void k_edge(
        const int* __restrict__ ei, const float* __restrict__ ea,
        const float* __restrict__ We, const float* __restrict__ asrc,
        const float* __restrict__ adst, const int* __restrict__ off,
        const int* __restrict__ rnk, float* __restrict__ rec) {
    __shared__ float sWe[NH * ED];
    if (threadIdx.x < NH * ED) sWe[threadIdx.x] = We[threadIdx.x];
    __syncthreads();
    int e = blockIdx.x * 256 + threadIdx.x;   // grid == NE/256 exactly
    int s = ei[e];
    int d = ei[NE + e];
    int r = rnk[e];
    float4 as4 = *(const float4*)(asrc + (long long)s * NH);
    float4 ad4 = *(const float4*)(adst + (long long)d * NH);
    int p = off[d] + r;     // off: 400KB, hot in L2
    f4v* ea4 = (f4v*)(const_cast<float*>(ea) + (long long)e * ED);
    f4v q0 = __builtin_nontemporal_load(ea4 + 0);
    f4v q1 = __builtin_nontemporal_load(ea4 + 1);
    f4v q2 = __builtin_nontemporal_load(ea4 + 2);
    f4v q3 = __builtin_nontemporal_load(ea4 + 3);
    float asv[4] = {as4.x, as4.y, as4.z, as4.w};
    float adv[4] = {ad4.x, ad4.y, ad4.z, ad4.w};
    unsigned int u[4];
#pragma unroll
    for (int h = 0; h < NH; h++) {
        const float* w = sWe + h * ED;
        float t = asv[h] + adv[h];
        t += q0.x * w[0]  + q0.y * w[1]  + q0.z * w[2]  + q0.w * w[3];
        t += q1.x * w[4]  + q1.y * w[5]  + q1.z * w[6]  + q1.w * w[7];
        t += q2.x * w[8]  + q2.y * w[9]  + q2.z * w[10] + q2.w * w[11];
        t += q3.x * w[12] + q3.y * w[13] + q3.z * w[14] + q3.w * w[15];
        t = (t >= 0.f) ? t : 0.2f * t;
        u[h] = __float_as_uint(expf(t));   // max score ~ +15 -> exp ~ 3e6, safe in f32
    }
    unsigned int ss = (unsigned int)s;
    u[0] = (u[0] & ~31u) | (ss & 31u);
    u[1] = (u[1] & ~15u) | ((ss >> 5) & 15u);
    u[2] = (u[2] & ~15u) | ((ss >> 9) & 15u);
    u[3] = (u[3] & ~15u) | ((ss >> 13) & 15u);
    f4v rv = {__uint_as_float(u[0]), __uint_as_float(u[1]),
              __uint_as_float(u[2]), __uint_as_float(u[3])};
    __builtin_nontemporal_store(rv, (f4v*)rec + p);
}

// ---------------- gather: normalize + accumulate + elu --------------
// wave per node; 4 groups of 16 lanes; group g handles edges j = start+g, +4...
// lane holds channels c16*4..c16*4+3 (float4); head h = c16>>2.
// no expf here: records already hold exp(score); src decoded from mantissa bits
__global__ __launch_bounds__(256) void k_gather(
        const int* __restrict__ off, float* __restrict__ rec,
        const float* __restrict__ Wh, const float* __restrict__ bias,
        float* __restrict__ out) {
    int node = blockIdx.x * 4 + (threadIdx.x >> 6);
    int lane = threadIdx.x & 63;
    if (node >= NN) return;
    int start = off[node], end = off[node + 1];
    int g = lane >> 4;       // edge group
    int c16 = lane & 15;     // channel quad
    int h = c16 >> 2;        // head

    float accx = 0.f, accy = 0.f, accz = 0.f, accw = 0.f;
    float dsum = 0.f;
#pragma unroll 2
    for (int j = start + g; j < end; j += 4) {
        f4v r = __builtin_nontemporal_load((f4v*)rec + j);   // 16-lane broadcast
        unsigned int b0 = __float_as_uint(r.x), b1 = __float_as_uint(r.y);
        unsigned int b2 = __float_as_uint(r.z), b3 = __float_as_uint(r.w);
        int src = (int)((b0 & 31u) | ((b1 & 15u) << 5) | ((b2 & 15u) << 9) | ((b3 & 15u) << 13));
        float ex = (h == 0) ? r.x : (h == 1) ? r.y : (h == 2) ? r.z : r.w;
        float4 w = *(const float4*)(Wh + (long long)src * OUTD + c16 * 4);
        accx += ex * w.x;
        accy += ex * w.y;
        accz += ex * w.z;
        accw += ex * w.w;
        dsum += ex;
    }
    // combine the 4 edge-groups (lanes l, l+16, l+32, l+48 share c16)
#pragma unroll
    for (int m = 16; m < 64; m <<= 1) {
        accx += __shfl_xor(accx, m);
        accy += __shfl_xor(accy, m);
        accz += __shfl_xor(accz, m);
        accw += __shfl_xor(accw, m);
        dsum += __shfl_xor(dsum, m);
    }
    if (g == 0) {
        float rden = 1.0f / (dsum + 1e-9f);
        const float4 b4 = *(const float4*)(bias + c16 * 4);
        float vx = accx * rden + b4.x;
        float vy = accy * rden + b4.y;
        float vz = accz * rden + b4.z;
        float vw = accw * rden + b4.w;
        vx = (vx > 0.f) ? vx : expm1f(vx);
        vy = (vy > 0.f) ? vy : expm1f(vy);
        vz = (vz > 0.f) ? vz : expm1f(vz);
        vw = (vw > 0.f) ? vw : expm1f(vw);
        f4v v = {vx, vy, vz, vw};
        __builtin_nontemporal_store(v, (f4v*)(out + (long long)node * OUTD) + c16);
    }
}

extern "C" void kernel_launch(void* const* d_in, const int* in_sizes, int n_in,
                              void* d_out, int out_size, void* d_ws, size_t ws_size,
                              hipStream_t stream) {
    const float* x     = (const float*)d_in[0];   // [NN,128]
    const int*   ei    = (const int*)d_in[1];     // [2,NE]
    const float* ea    = (const float*)d_in[2];   // [NE,16]
    const float* Wn    = (const float*)d_in[3];   // [64,128]
    const float* We    = (const float*)d_in[4];   // [4,16]
    const float* att_s = (const float*)d_in[5];   // 64
    const float* att_d = (const float*)d_in[6];   // 64
    const float* bias  = (const float*)d_in[7];   // 64
    float* out = (float*)d_out;

    float* ws   = (float*)d_ws;
    float* Wh   = ws;                                   // NN*64 f
    float* asrc = Wh + (size_t)NN * OUTD;               // NN*4 f
    float* adst = asrc + (size_t)NN * NH;               // NN*4 f
    float* rec  = adst + (size_t)NN * NH;               // NE*4 f (packed 16B records)
    int*   deg  = (int*)(rec + (size_t)NE * 4);         // NN i
    int*   offA = deg + NN;                             // NN i
    int*   off  = offA + NN;                            // NN+1 i
    int*   bsum = off + NN + 1;                         // 128 i
    int*   rnk  = bsum + 128;                           // NE i

    k_zero<<<(NN + 255) / 256, 256, 0, stream>>>(deg);
    k_node<<<NN / 32, 512, 0, stream>>>(x, Wn, att_s, att_d, Wh, asrc, adst,
                                        ei, deg, rnk);
    k_scan1<<<NB1, 256, 0, stream>>>(deg, offA, bsum);
    k_scan2<<<1, 128, 0, stream>>>(bsum);
    k_scan3<<<(NN + 255) / 256, 256, 0, stream>>>(offA, bsum, off);
    k_edge<<<(NE + 255) / 256, 256, 0, stream>>>(ei, ea, We, asrc, adst, off, rnk, rec);
    k_gather<<<(NN + 3) / 4, 256, 0, stream>>>(off, rec, Wh, bias, out);
}